// Round 8
// baseline (962.804 us; speedup 1.0000x reference)
//
#include <hip/hip_runtime.h>

#define NTHR 256
#define NCHUNK 1024            // B / 256 slot-chunks (cnt/bp entries)

typedef unsigned long long u64;
typedef float v2 __attribute__((ext_vector_type(2)));

// ---------------------------------------------------------------------------
// index of the (n+1)-th set bit of m (n 0-based), 6-step binary search
__device__ __forceinline__ int nth_set_bit(u64 m, unsigned n) {
    int pos = 0;
#pragma unroll
    for (int st = 32; st; st >>= 1) {
        u64 low = (1ull << (pos + st)) - 1ull;
        if ((unsigned)__popcll(m & low) <= n) pos += st;
    }
    return pos;
}

// ---------------------------------------------------------------------------
// MLP + hysteresis. Packed-FP32 pairs over output neurons (j, j+1).
// Per-ELEMENT arithmetic (k-sequential fma from 0, +bias, relu, j-sequential
// layer-3 accumulation) is byte-identical to the validated scalar version.
// h1 halves are consumed via .xx/.yy swizzles so the backend can fold them
// into VOP3P op_sel instead of materializing a splat array (VGPR pressure).
// ---------------------------------------------------------------------------
__device__ __forceinline__ void mlp_update(
    const float lin, const float x, const float isOn,
    const float* __restrict__ W1, const float* __restrict__ b1,
    const float* __restrict__ W2, const float* __restrict__ b2,
    const float* __restrict__ W3, const float* __restrict__ b3,
    float& x_new, float& isOn_new, bool& off)
{
    off = (isOn <= 0.5f);

    const v2* __restrict__ W1r0 = (const v2*)W1;          // row 0 (lin weights)
    const v2* __restrict__ W1r1 = (const v2*)(W1 + 32);   // row 1 (x weights)
    const v2* __restrict__ b1p  = (const v2*)b1;
    const v2* __restrict__ b2p  = (const v2*)b2;

    const v2 linv = { lin, lin };
    const v2 xv   = { x, x };
    const v2 zero = { 0.0f, 0.0f };

    // layer 1: 16 neuron-pairs; per element: mul, fma, add, relu (same order)
    v2 h1v[16];
#pragma unroll
    for (int jp = 0; jp < 16; ++jp) {
        v2 a = linv * W1r0[jp];                           // v_pk_mul_f32
        a = __builtin_elementwise_fma(xv, W1r1[jp], a);   // v_pk_fma_f32
        a = a + b1p[jp];                                  // v_pk_add_f32
        h1v[jp] = __builtin_elementwise_max(a, zero);     // v_pk_max_f32
    }

    // layer 2 + fused layer 3 (layer-3 accumulation stays scalar j-order)
    float o = 0.0f;
#pragma unroll
    for (int jp = 0; jp < 16; ++jp) {
        v2 a = { 0.0f, 0.0f };
        const v2* __restrict__ w2col = (const v2*)(W2) + jp;  // stride 16 v2/row
#pragma unroll
        for (int kp = 0; kp < 16; ++kp) {
            // k = 2*kp and 2*kp+1, strictly in order (op_sel-foldable swizzle)
            a = __builtin_elementwise_fma(h1v[kp].xx, w2col[(2 * kp) * 16], a);
            a = __builtin_elementwise_fma(h1v[kp].yy, w2col[(2 * kp + 1) * 16], a);
        }
        a = a + b2p[jp];
        const float ax = fmaxf(a.x, 0.0f);
        const float ay = fmaxf(a.y, 0.0f);
        o = fmaf(ax, W3[2 * jp], o);
        o = fmaf(ay, W3[2 * jp + 1], o);
    }
    o += b3[0];

    const float plant = o * 10.0f;
    const float tm = x - plant;
    x_new = off ? tm : tm + 10.0f;
    isOn_new = off ? ((x_new <= 66.0f) ? 1.0f : isOn)
                   : ((x_new > 78.0f) ? 0.0f : isOn);
}

// ---------------------------------------------------------------------------
// source slot for destination slot i, given bp[] (excl off-prefix per chunk,
// in LDS), total off count T, and per-wave off masks mskP
// ---------------------------------------------------------------------------
__device__ __forceinline__ int resolve_src(const unsigned* bp,
                                           const u64* __restrict__ mskP,
                                           unsigned T, unsigned i)
{
    if (i < T) {
        const unsigned r = i;
        int b = 0;
#pragma unroll
        for (int st = NCHUNK / 2; st; st >>= 1) {
            const int nb = b + st;
            if (nb < NCHUNK && bp[nb] <= r) b = nb;
        }
        unsigned rr = r - bp[b];
        const u64 m0 = mskP[4 * b],     m1 = mskP[4 * b + 1];
        const u64 m2 = mskP[4 * b + 2], m3 = mskP[4 * b + 3];
        const unsigned p0 = __popcll(m0), p1 = __popcll(m1), p2 = __popcll(m2);
        int w; u64 m; unsigned nn;
        if (rr < p0)                { w = 0; m = m0; nn = rr; }
        else if (rr < p0 + p1)      { w = 1; m = m1; nn = rr - p0; }
        else if (rr < p0 + p1 + p2) { w = 2; m = m2; nn = rr - p0 - p1; }
        else                        { w = 3; m = m3; nn = rr - p0 - p1 - p2; }
        return b * NTHR + w * 64 + nth_set_bit(m, nn);
    } else {
        const unsigned q = i - T;
        int b = 0;
#pragma unroll
        for (int st = NCHUNK / 2; st; st >>= 1) {
            const int nb = b + st;
            if (nb < NCHUNK && ((unsigned)NTHR * (unsigned)nb - bp[nb]) <= q) b = nb;
        }
        unsigned qq = q - ((unsigned)NTHR * (unsigned)b - bp[b]);
        const u64 m0 = ~mskP[4 * b],     m1 = ~mskP[4 * b + 1];
        const u64 m2 = ~mskP[4 * b + 2], m3 = ~mskP[4 * b + 3];
        const unsigned p0 = __popcll(m0), p1 = __popcll(m1), p2 = __popcll(m2);
        int w; u64 m; unsigned nn;
        if (qq < p0)                { w = 0; m = m0; nn = qq; }
        else if (qq < p0 + p1)      { w = 1; m = m1; nn = qq - p0; }
        else if (qq < p0 + p1 + p2) { w = 2; m = m2; nn = qq - p0 - p1; }
        else                        { w = 3; m = m3; nn = qq - p0 - p1 - p2; }
        return b * NTHR + w * 64 + nth_set_bit(m, nn);
    }
}

// ---------------------------------------------------------------------------
// One kernel per simulation step (verified round-2 structure).
//   mode 0: first step  — x from input, isOn=0, no pull
//   mode 1: middle step — pull permuted state, write traj row t-1, compute
//   mode 2: final pull  — pull only, write last traj row
// __launch_bounds__(256, 8): cap 64 VGPR -> 8 blocks/CU for latency hiding
// during the pull's dependent-load chain.
// ---------------------------------------------------------------------------
__global__ __launch_bounds__(NTHR, 8) void fused_kernel(
    const float2* __restrict__ inp,
    const float* __restrict__ W1, const float* __restrict__ b1,
    const float* __restrict__ W2, const float* __restrict__ b2,
    const float* __restrict__ W3, const float* __restrict__ b3,
    const float2* __restrict__ stPrev, const unsigned* __restrict__ cntPrev,
    const u64* __restrict__ mskPrev,
    float2* __restrict__ stNew, unsigned* __restrict__ cntNew,
    u64* __restrict__ mskNew,
    float* __restrict__ outRow,
    int mode)
{
    const int tid  = threadIdx.x;
    const int lane = tid & 63;
    const int wv   = tid >> 6;
    const int i    = blockIdx.x * NTHR + tid;

    float x, isOn;
    if (mode == 0) {
        const float2 iv = inp[i];
        x = iv.y; isOn = 0.0f;
    } else {
        __shared__ unsigned bp[NCHUNK];
        __shared__ unsigned wsum[NTHR / 64];
        const uint4 cc = ((const uint4*)cntPrev)[tid];
        const unsigned s = cc.x + cc.y + cc.z + cc.w;
        unsigned inc = s;
#pragma unroll
        for (int d = 1; d < 64; d <<= 1) {
            unsigned v = __shfl_up(inc, d);
            if (lane >= d) inc += v;
        }
        if (lane == 63) wsum[wv] = inc;
        __syncthreads();
        unsigned T = 0, wexcl = 0;
#pragma unroll
        for (int w = 0; w < NTHR / 64; ++w) {
            T += wsum[w];
            if (w < wv) wexcl += wsum[w];
        }
        unsigned r0 = wexcl + inc - s;
        const unsigned base = tid * 4;
        bp[base]     = r0; r0 += cc.x;
        bp[base + 1] = r0; r0 += cc.y;
        bp[base + 2] = r0; r0 += cc.z;
        bp[base + 3] = r0;
        __syncthreads();

        const int src = resolve_src(bp, mskPrev, T, (unsigned)i);
        const float2 sv = stPrev[src];
        x = sv.x; isOn = sv.y;
        outRow[i] = x;
        if (mode == 2) return;
    }

    const float lin = inp[i].x;
    float x_new, isOn_new;
    bool off;
    mlp_update(lin, x, isOn, W1, b1, W2, b2, W3, b3, x_new, isOn_new, off);

    stNew[i] = make_float2(x_new, isOn_new);

    const u64 m = __ballot(off);
    __shared__ unsigned wOff[NTHR / 64];
    if (lane == 0) { mskNew[i >> 6] = m; wOff[wv] = (unsigned)__popcll(m); }
    __syncthreads();
    if (tid == 0) {
        unsigned ssum = 0;
#pragma unroll
        for (int w = 0; w < NTHR / 64; ++w) ssum += wOff[w];
        cntNew[blockIdx.x] = ssum;
    }
}

// ---------------------------------------------------------------------------
extern "C" void kernel_launch(void* const* d_in, const int* in_sizes, int n_in,
                              void* d_out, int out_size, void* d_ws, size_t ws_size,
                              hipStream_t stream)
{
    const float2* inp = (const float2*)d_in[0];
    const float* W1 = (const float*)d_in[1];
    const float* b1 = (const float*)d_in[2];
    const float* W2 = (const float*)d_in[3];
    const float* b2 = (const float*)d_in[4];
    const float* W3 = (const float*)d_in[5];
    const float* b3 = (const float*)d_in[6];
    float* out = (float*)d_out;

    const int B = in_sizes[0] / 2;          // 262144
    const int nsteps = out_size / B;        // 40
    const int nblk = B / NTHR;              // 1024

    float2*   st0 = (float2*)d_ws;
    float2*   st1 = st0 + B;
    unsigned* cnt0 = (unsigned*)(st1 + B);
    unsigned* cnt1 = cnt0 + NCHUNK;
    u64*      msk0 = (u64*)(cnt1 + NCHUNK);
    u64*      msk1 = msk0 + (B / 64);

    // step 0: no pull
    fused_kernel<<<nblk, NTHR, 0, stream>>>(inp, W1, b1, W2, b2, W3, b3,
                                            st0, cnt0, msk0,
                                            st0, cnt0, msk0, nullptr, 0);
    // steps 1..nsteps-1: pull prev (writes traj row t-1) + compute step t
    for (int t = 1; t < nsteps; ++t) {
        const bool odd = (t & 1);
        const float2*   stP  = odd ? st0  : st1;
        const unsigned* cntP = odd ? cnt0 : cnt1;
        const u64*      mskP = odd ? msk0 : msk1;
        float2*   stN  = odd ? st1  : st0;
        unsigned* cntN = odd ? cnt1 : cnt0;
        u64*      mskN = odd ? msk1 : msk0;
        fused_kernel<<<nblk, NTHR, 0, stream>>>(inp, W1, b1, W2, b2, W3, b3,
                                                stP, cntP, mskP,
                                                stN, cntN, mskN,
                                                out + (size_t)(t - 1) * B, 1);
    }
    // final pull-only: traj row nsteps-1
    {
        const bool odd = (nsteps & 1);
        const float2*   stP  = odd ? st0  : st1;
        const unsigned* cntP = odd ? cnt0 : cnt1;
        const u64*      mskP = odd ? msk0 : msk1;
        fused_kernel<<<nblk, NTHR, 0, stream>>>(inp, W1, b1, W2, b2, W3, b3,
                                                stP, cntP, mskP,
                                                st0, cnt0, msk0,
                                                out + (size_t)(nsteps - 1) * B, 2);
    }
}

// Round 9
// 426.114 us; speedup vs baseline: 2.2595x; 2.2595x over previous
//
#include <hip/hip_runtime.h>

#define NTHR 256
#define B_TOT 262144
#define NCHUNK 1024            // B / 256 slot-chunks (cnt/bp entries)
#define NBLK 512               // 2 elements per thread: i0 and i0 + B/2

typedef unsigned long long u64;
typedef float v2 __attribute__((ext_vector_type(2)));

// ---------------------------------------------------------------------------
// index of the (n+1)-th set bit of m (n 0-based), 6-step binary search
__device__ __forceinline__ int nth_set_bit(u64 m, unsigned n) {
    int pos = 0;
#pragma unroll
    for (int st = 32; st; st >>= 1) {
        u64 low = (1ull << (pos + st)) - 1ull;
        if ((unsigned)__popcll(m & low) <= n) pos += st;
    }
    return pos;
}

// ---------------------------------------------------------------------------
// MLP + hysteresis. Packed-FP32 pairs over output neurons (j, j+1).
// Per-ELEMENT arithmetic (k-sequential fma from 0, +bias, relu, j-sequential
// layer-3 accumulation) is byte-identical to the validated scalar version.
// ---------------------------------------------------------------------------
__device__ __forceinline__ void mlp_update(
    const float lin, const float x, const float isOn,
    const float* __restrict__ W1, const float* __restrict__ b1,
    const float* __restrict__ W2, const float* __restrict__ b2,
    const float* __restrict__ W3, const float* __restrict__ b3,
    float& x_new, float& isOn_new, bool& off)
{
    off = (isOn <= 0.5f);

    const v2* __restrict__ W1r0 = (const v2*)W1;          // row 0 (lin weights)
    const v2* __restrict__ W1r1 = (const v2*)(W1 + 32);   // row 1 (x weights)
    const v2* __restrict__ b1p  = (const v2*)b1;
    const v2* __restrict__ b2p  = (const v2*)b2;

    const v2 linv = { lin, lin };
    const v2 xv   = { x, x };
    const v2 zero = { 0.0f, 0.0f };

    // layer 1: 16 neuron-pairs; per element: mul, fma, add, relu (same order)
    v2 h1v[16];
#pragma unroll
    for (int jp = 0; jp < 16; ++jp) {
        v2 a = linv * W1r0[jp];                           // v_pk_mul_f32
        a = __builtin_elementwise_fma(xv, W1r1[jp], a);   // v_pk_fma_f32
        a = a + b1p[jp];                                  // v_pk_add_f32
        h1v[jp] = __builtin_elementwise_max(a, zero);     // v_pk_max_f32
    }

    // layer 2 + fused layer 3 (layer-3 accumulation stays scalar j-order)
    float o = 0.0f;
#pragma unroll
    for (int jp = 0; jp < 16; ++jp) {
        v2 a = { 0.0f, 0.0f };
        const v2* __restrict__ w2col = (const v2*)(W2) + jp;  // stride 16 v2/row
#pragma unroll
        for (int kp = 0; kp < 16; ++kp) {
            a = __builtin_elementwise_fma(h1v[kp].xx, w2col[(2 * kp) * 16], a);
            a = __builtin_elementwise_fma(h1v[kp].yy, w2col[(2 * kp + 1) * 16], a);
        }
        a = a + b2p[jp];
        const float ax = fmaxf(a.x, 0.0f);
        const float ay = fmaxf(a.y, 0.0f);
        o = fmaf(ax, W3[2 * jp], o);
        o = fmaf(ay, W3[2 * jp + 1], o);
    }
    o += b3[0];

    const float plant = o * 10.0f;
    const float tm = x - plant;
    x_new = off ? tm : tm + 10.0f;
    isOn_new = off ? ((x_new <= 66.0f) ? 1.0f : isOn)
                   : ((x_new > 78.0f) ? 0.0f : isOn);
}

// ---------------------------------------------------------------------------
// source slot for destination slot i, given bp[] (excl off-prefix per chunk,
// in LDS), total off count T, and per-wave off masks mskP
// ---------------------------------------------------------------------------
__device__ __forceinline__ int resolve_src(const unsigned* bp,
                                           const u64* __restrict__ mskP,
                                           unsigned T, unsigned i)
{
    if (i < T) {
        const unsigned r = i;
        int b = 0;
#pragma unroll
        for (int st = NCHUNK / 2; st; st >>= 1) {
            const int nb = b + st;
            if (nb < NCHUNK && bp[nb] <= r) b = nb;
        }
        unsigned rr = r - bp[b];
        const u64 m0 = mskP[4 * b],     m1 = mskP[4 * b + 1];
        const u64 m2 = mskP[4 * b + 2], m3 = mskP[4 * b + 3];
        const unsigned p0 = __popcll(m0), p1 = __popcll(m1), p2 = __popcll(m2);
        int w; u64 m; unsigned nn;
        if (rr < p0)                { w = 0; m = m0; nn = rr; }
        else if (rr < p0 + p1)      { w = 1; m = m1; nn = rr - p0; }
        else if (rr < p0 + p1 + p2) { w = 2; m = m2; nn = rr - p0 - p1; }
        else                        { w = 3; m = m3; nn = rr - p0 - p1 - p2; }
        return b * 256 + w * 64 + nth_set_bit(m, nn);
    } else {
        const unsigned q = i - T;
        int b = 0;
#pragma unroll
        for (int st = NCHUNK / 2; st; st >>= 1) {
            const int nb = b + st;
            if (nb < NCHUNK && (256u * (unsigned)nb - bp[nb]) <= q) b = nb;
        }
        unsigned qq = q - (256u * (unsigned)b - bp[b]);
        const u64 m0 = ~mskP[4 * b],     m1 = ~mskP[4 * b + 1];
        const u64 m2 = ~mskP[4 * b + 2], m3 = ~mskP[4 * b + 3];
        const unsigned p0 = __popcll(m0), p1 = __popcll(m1), p2 = __popcll(m2);
        int w; u64 m; unsigned nn;
        if (qq < p0)                { w = 0; m = m0; nn = qq; }
        else if (qq < p0 + p1)      { w = 1; m = m1; nn = qq - p0; }
        else if (qq < p0 + p1 + p2) { w = 2; m = m2; nn = qq - p0 - p1; }
        else                        { w = 3; m = m3; nn = qq - p0 - p1 - p2; }
        return b * 256 + w * 64 + nth_set_bit(m, nn);
    }
}

// ---------------------------------------------------------------------------
// One kernel per simulation step; 512 blocks, 2 elements per thread
// (slots i0 = blk*256+tid and i1 = i0 + B/2; chunk layout unchanged).
//   mode 0: first step  — x from input, isOn=0, no pull
//   mode 1: middle step — pull permuted state, write traj row t-1, compute
//   mode 2: final pull  — pull only, write last traj row
// __launch_bounds__(256,4): VERIFIED config (VGPR cap 128, no spills).
// ---------------------------------------------------------------------------
__global__ __launch_bounds__(NTHR, 4) void fused_kernel(
    const float2* __restrict__ inp,
    const float* __restrict__ W1, const float* __restrict__ b1,
    const float* __restrict__ W2, const float* __restrict__ b2,
    const float* __restrict__ W3, const float* __restrict__ b3,
    const float2* __restrict__ stPrev, const unsigned* __restrict__ cntPrev,
    const u64* __restrict__ mskPrev,
    float2* __restrict__ stNew, unsigned* __restrict__ cntNew,
    u64* __restrict__ mskNew,
    float* __restrict__ outRow,
    int mode)
{
    const int tid  = threadIdx.x;
    const int lane = tid & 63;
    const int wv   = tid >> 6;
    const int i0   = blockIdx.x * NTHR + tid;
    const int i1   = i0 + (B_TOT / 2);

    const float lin0 = inp[i0].x;        // issue early; overlaps scan latency
    const float lin1 = inp[i1].x;

    float x0, on0, x1, on1;
    if (mode == 0) {
        x0 = inp[i0].y; on0 = 0.0f;
        x1 = inp[i1].y; on1 = 0.0f;
    } else {
        __shared__ unsigned bp[NCHUNK];
        __shared__ unsigned wsum[NTHR / 64];
        // cnt scan: 1024 counts, uint4 per thread
        const uint4 cc = ((const uint4*)cntPrev)[tid];
        const unsigned s = cc.x + cc.y + cc.z + cc.w;
        unsigned inc = s;
#pragma unroll
        for (int d = 1; d < 64; d <<= 1) {
            unsigned v = __shfl_up(inc, d);
            if (lane >= d) inc += v;
        }
        if (lane == 63) wsum[wv] = inc;
        __syncthreads();
        unsigned T = 0, wexcl = 0;
#pragma unroll
        for (int w = 0; w < NTHR / 64; ++w) {
            T += wsum[w];
            if (w < wv) wexcl += wsum[w];
        }
        unsigned r0 = wexcl + inc - s;
        const unsigned base = tid * 4;
        bp[base]     = r0; r0 += cc.x;
        bp[base + 1] = r0; r0 += cc.y;
        bp[base + 2] = r0; r0 += cc.z;
        bp[base + 3] = r0;
        __syncthreads();

        const int s0 = resolve_src(bp, mskPrev, T, (unsigned)i0);
        const int s1 = resolve_src(bp, mskPrev, T, (unsigned)i1);
        const float2 v0 = stPrev[s0];
        const float2 v1 = stPrev[s1];
        x0 = v0.x; on0 = v0.y;
        x1 = v1.x; on1 = v1.y;
        outRow[i0] = x0;
        outRow[i1] = x1;
        if (mode == 2) return;
    }

    float xn0, onn0, xn1, onn1;
    bool off0, off1;
    mlp_update(lin0, x0, on0, W1, b1, W2, b2, W3, b3, xn0, onn0, off0);
    mlp_update(lin1, x1, on1, W1, b1, W2, b2, W3, b3, xn1, onn1, off1);

    stNew[i0] = make_float2(xn0, onn0);
    stNew[i1] = make_float2(xn1, onn1);

    const u64 m0 = __ballot(off0);
    const u64 m1 = __ballot(off1);
    __shared__ unsigned wOff0[NTHR / 64], wOff1[NTHR / 64];
    if (lane == 0) {
        mskNew[i0 >> 6] = m0;
        mskNew[i1 >> 6] = m1;
        wOff0[wv] = (unsigned)__popcll(m0);
        wOff1[wv] = (unsigned)__popcll(m1);
    }
    __syncthreads();
    if (tid == 0) {
        unsigned sa = 0, sb = 0;
#pragma unroll
        for (int w = 0; w < NTHR / 64; ++w) { sa += wOff0[w]; sb += wOff1[w]; }
        cntNew[blockIdx.x] = sa;               // chunk of i0
        cntNew[blockIdx.x + NBLK] = sb;        // chunk of i1
    }
}

// ---------------------------------------------------------------------------
extern "C" void kernel_launch(void* const* d_in, const int* in_sizes, int n_in,
                              void* d_out, int out_size, void* d_ws, size_t ws_size,
                              hipStream_t stream)
{
    const float2* inp = (const float2*)d_in[0];
    const float* W1 = (const float*)d_in[1];
    const float* b1 = (const float*)d_in[2];
    const float* W2 = (const float*)d_in[3];
    const float* b2 = (const float*)d_in[4];
    const float* W3 = (const float*)d_in[5];
    const float* b3 = (const float*)d_in[6];
    float* out = (float*)d_out;

    const int B = in_sizes[0] / 2;          // 262144
    const int nsteps = out_size / B;        // 40

    float2*   st0 = (float2*)d_ws;
    float2*   st1 = st0 + B;
    unsigned* cnt0 = (unsigned*)(st1 + B);
    unsigned* cnt1 = cnt0 + NCHUNK;
    u64*      msk0 = (u64*)(cnt1 + NCHUNK);
    u64*      msk1 = msk0 + (B / 64);

    // step 0: no pull
    fused_kernel<<<NBLK, NTHR, 0, stream>>>(inp, W1, b1, W2, b2, W3, b3,
                                            st0, cnt0, msk0,
                                            st0, cnt0, msk0, nullptr, 0);
    // steps 1..nsteps-1: pull prev (writes traj row t-1) + compute step t
    for (int t = 1; t < nsteps; ++t) {
        const bool odd = (t & 1);
        const float2*   stP  = odd ? st0  : st1;
        const unsigned* cntP = odd ? cnt0 : cnt1;
        const u64*      mskP = odd ? msk0 : msk1;
        float2*   stN  = odd ? st1  : st0;
        unsigned* cntN = odd ? cnt1 : cnt0;
        u64*      mskN = odd ? msk1 : msk0;
        fused_kernel<<<NBLK, NTHR, 0, stream>>>(inp, W1, b1, W2, b2, W3, b3,
                                                stP, cntP, mskP,
                                                stN, cntN, mskN,
                                                out + (size_t)(t - 1) * B, 1);
    }
    // final pull-only: traj row nsteps-1
    {
        const bool odd = (nsteps & 1);
        const float2*   stP  = odd ? st0  : st1;
        const unsigned* cntP = odd ? cnt0 : cnt1;
        const u64*      mskP = odd ? msk0 : msk1;
        fused_kernel<<<NBLK, NTHR, 0, stream>>>(inp, W1, b1, W2, b2, W3, b3,
                                                stP, cntP, mskP,
                                                st0, cnt0, msk0,
                                                out + (size_t)(nsteps - 1) * B, 2);
    }
}

// Round 10
// 396.201 us; speedup vs baseline: 2.4301x; 1.0755x over previous
//
#include <hip/hip_runtime.h>

#define NTHR 512               // threads per block (8 waves)
#define NBLK 512               // blocks: NBLK*NTHR = B = 262144, 1 elem/thread
#define NCHUNK 1024            // 256-slot chunks (cnt/bp entries) — layout unchanged

typedef unsigned long long u64;
typedef float v2 __attribute__((ext_vector_type(2)));

// ---------------------------------------------------------------------------
// index of the (n+1)-th set bit of m (n 0-based), 6-step binary search
__device__ __forceinline__ int nth_set_bit(u64 m, unsigned n) {
    int pos = 0;
#pragma unroll
    for (int st = 32; st; st >>= 1) {
        u64 low = (1ull << (pos + st)) - 1ull;
        if ((unsigned)__popcll(m & low) <= n) pos += st;
    }
    return pos;
}

// ---------------------------------------------------------------------------
// MLP + hysteresis. Packed-FP32 pairs over output neurons (j, j+1).
// Per-ELEMENT arithmetic (k-sequential fma from 0, +bias, relu, j-sequential
// layer-3 accumulation) is byte-identical to the validated scalar version.
// ---------------------------------------------------------------------------
__device__ __forceinline__ void mlp_update(
    const float lin, const float x, const float isOn,
    const float* __restrict__ W1, const float* __restrict__ b1,
    const float* __restrict__ W2, const float* __restrict__ b2,
    const float* __restrict__ W3, const float* __restrict__ b3,
    float& x_new, float& isOn_new, bool& off)
{
    off = (isOn <= 0.5f);

    const v2* __restrict__ W1r0 = (const v2*)W1;          // row 0 (lin weights)
    const v2* __restrict__ W1r1 = (const v2*)(W1 + 32);   // row 1 (x weights)
    const v2* __restrict__ b1p  = (const v2*)b1;
    const v2* __restrict__ b2p  = (const v2*)b2;

    const v2 linv = { lin, lin };
    const v2 xv   = { x, x };
    const v2 zero = { 0.0f, 0.0f };

    // layer 1: 16 neuron-pairs; per element: mul, fma, add, relu (same order)
    v2 h1v[16];
#pragma unroll
    for (int jp = 0; jp < 16; ++jp) {
        v2 a = linv * W1r0[jp];                           // v_pk_mul_f32
        a = __builtin_elementwise_fma(xv, W1r1[jp], a);   // v_pk_fma_f32
        a = a + b1p[jp];                                  // v_pk_add_f32
        h1v[jp] = __builtin_elementwise_max(a, zero);     // v_pk_max_f32
    }

    // layer 2 + fused layer 3 (layer-3 accumulation stays scalar j-order)
    float o = 0.0f;
#pragma unroll
    for (int jp = 0; jp < 16; ++jp) {
        v2 a = { 0.0f, 0.0f };
        const v2* __restrict__ w2col = (const v2*)(W2) + jp;  // stride 16 v2/row
#pragma unroll
        for (int kp = 0; kp < 16; ++kp) {
            a = __builtin_elementwise_fma(h1v[kp].xx, w2col[(2 * kp) * 16], a);
            a = __builtin_elementwise_fma(h1v[kp].yy, w2col[(2 * kp + 1) * 16], a);
        }
        a = a + b2p[jp];
        const float ax = fmaxf(a.x, 0.0f);
        const float ay = fmaxf(a.y, 0.0f);
        o = fmaf(ax, W3[2 * jp], o);
        o = fmaf(ay, W3[2 * jp + 1], o);
    }
    o += b3[0];

    const float plant = o * 10.0f;
    const float tm = x - plant;
    x_new = off ? tm : tm + 10.0f;
    isOn_new = off ? ((x_new <= 66.0f) ? 1.0f : isOn)
                   : ((x_new > 78.0f) ? 0.0f : isOn);
}

// ---------------------------------------------------------------------------
// source slot for destination slot i, given bp[] (excl off-prefix per 256-slot
// chunk, in LDS), total off count T, and per-wave off masks mskP
// ---------------------------------------------------------------------------
__device__ __forceinline__ int resolve_src(const unsigned* bp,
                                           const u64* __restrict__ mskP,
                                           unsigned T, unsigned i)
{
    if (i < T) {
        const unsigned r = i;
        int b = 0;
#pragma unroll
        for (int st = NCHUNK / 2; st; st >>= 1) {
            const int nb = b + st;
            if (nb < NCHUNK && bp[nb] <= r) b = nb;
        }
        unsigned rr = r - bp[b];
        const u64 m0 = mskP[4 * b],     m1 = mskP[4 * b + 1];
        const u64 m2 = mskP[4 * b + 2], m3 = mskP[4 * b + 3];
        const unsigned p0 = __popcll(m0), p1 = __popcll(m1), p2 = __popcll(m2);
        int w; u64 m; unsigned nn;
        if (rr < p0)                { w = 0; m = m0; nn = rr; }
        else if (rr < p0 + p1)      { w = 1; m = m1; nn = rr - p0; }
        else if (rr < p0 + p1 + p2) { w = 2; m = m2; nn = rr - p0 - p1; }
        else                        { w = 3; m = m3; nn = rr - p0 - p1 - p2; }
        return b * 256 + w * 64 + nth_set_bit(m, nn);
    } else {
        const unsigned q = i - T;
        int b = 0;
#pragma unroll
        for (int st = NCHUNK / 2; st; st >>= 1) {
            const int nb = b + st;
            if (nb < NCHUNK && (256u * (unsigned)nb - bp[nb]) <= q) b = nb;
        }
        unsigned qq = q - (256u * (unsigned)b - bp[b]);
        const u64 m0 = ~mskP[4 * b],     m1 = ~mskP[4 * b + 1];
        const u64 m2 = ~mskP[4 * b + 2], m3 = ~mskP[4 * b + 3];
        const unsigned p0 = __popcll(m0), p1 = __popcll(m1), p2 = __popcll(m2);
        int w; u64 m; unsigned nn;
        if (qq < p0)                { w = 0; m = m0; nn = qq; }
        else if (qq < p0 + p1)      { w = 1; m = m1; nn = qq - p0; }
        else if (qq < p0 + p1 + p2) { w = 2; m = m2; nn = qq - p0 - p1; }
        else                        { w = 3; m = m3; nn = qq - p0 - p1 - p2; }
        return b * 256 + w * 64 + nth_set_bit(m, nn);
    }
}

// ---------------------------------------------------------------------------
// One kernel per simulation step; 512 blocks x 512 threads, 1 elem/thread.
// Each block covers 2 chunks (slots blk*512 .. blk*512+511); publishes 2 cnt
// entries and 8 wave-masks. Consumer logic identical to the verified kernel.
//   mode 0: first step  — x from input, isOn=0, no pull
//   mode 1: middle step — pull permuted state, write traj row t-1, compute
//   mode 2: final pull  — pull only, write last traj row
// ---------------------------------------------------------------------------
__global__ __launch_bounds__(NTHR, 2) void fused_kernel(
    const float2* __restrict__ inp,
    const float* __restrict__ W1, const float* __restrict__ b1,
    const float* __restrict__ W2, const float* __restrict__ b2,
    const float* __restrict__ W3, const float* __restrict__ b3,
    const float2* __restrict__ stPrev, const unsigned* __restrict__ cntPrev,
    const u64* __restrict__ mskPrev,
    float2* __restrict__ stNew, unsigned* __restrict__ cntNew,
    u64* __restrict__ mskNew,
    float* __restrict__ outRow,
    int mode)
{
    const int tid  = threadIdx.x;
    const int lane = tid & 63;
    const int wv   = tid >> 6;                 // 0..7
    const int i    = blockIdx.x * NTHR + tid;

    const float lin = inp[i].x;                // early issue

    float x, isOn;
    if (mode == 0) {
        x = inp[i].y; isOn = 0.0f;
    } else {
        __shared__ unsigned bp[NCHUNK];
        __shared__ unsigned wsum[NTHR / 64];
        // cnt scan: 1024 counts, uint2 per thread (512 threads)
        const uint2 cc = ((const uint2*)cntPrev)[tid];
        const unsigned s = cc.x + cc.y;
        unsigned inc = s;
#pragma unroll
        for (int d = 1; d < 64; d <<= 1) {
            unsigned v = __shfl_up(inc, d);
            if (lane >= d) inc += v;
        }
        if (lane == 63) wsum[wv] = inc;
        __syncthreads();
        unsigned T = 0, wexcl = 0;
#pragma unroll
        for (int w = 0; w < NTHR / 64; ++w) {
            T += wsum[w];
            if (w < wv) wexcl += wsum[w];
        }
        unsigned r0 = wexcl + inc - s;         // exclusive prefix for this thread
        bp[2 * tid]     = r0;
        bp[2 * tid + 1] = r0 + cc.x;
        __syncthreads();

        const int src = resolve_src(bp, mskPrev, T, (unsigned)i);
        const float2 sv = stPrev[src];
        x = sv.x; isOn = sv.y;
        outRow[i] = x;
        if (mode == 2) return;
    }

    float x_new, isOn_new;
    bool off;
    mlp_update(lin, x, isOn, W1, b1, W2, b2, W3, b3, x_new, isOn_new, off);

    stNew[i] = make_float2(x_new, isOn_new);

    const u64 m = __ballot(off);
    __shared__ unsigned wOff[NTHR / 64];
    if (lane == 0) { mskNew[i >> 6] = m; wOff[wv] = (unsigned)__popcll(m); }
    __syncthreads();
    if (tid == 0) {
        unsigned sa = 0, sb = 0;
#pragma unroll
        for (int w = 0; w < 4; ++w) { sa += wOff[w]; sb += wOff[4 + w]; }
        cntNew[2 * blockIdx.x]     = sa;       // chunk of waves 0-3
        cntNew[2 * blockIdx.x + 1] = sb;       // chunk of waves 4-7
    }
}

// ---------------------------------------------------------------------------
extern "C" void kernel_launch(void* const* d_in, const int* in_sizes, int n_in,
                              void* d_out, int out_size, void* d_ws, size_t ws_size,
                              hipStream_t stream)
{
    const float2* inp = (const float2*)d_in[0];
    const float* W1 = (const float*)d_in[1];
    const float* b1 = (const float*)d_in[2];
    const float* W2 = (const float*)d_in[3];
    const float* b2 = (const float*)d_in[4];
    const float* W3 = (const float*)d_in[5];
    const float* b3 = (const float*)d_in[6];
    float* out = (float*)d_out;

    const int B = in_sizes[0] / 2;          // 262144
    const int nsteps = out_size / B;        // 40

    float2*   st0 = (float2*)d_ws;
    float2*   st1 = st0 + B;
    unsigned* cnt0 = (unsigned*)(st1 + B);
    unsigned* cnt1 = cnt0 + NCHUNK;
    u64*      msk0 = (u64*)(cnt1 + NCHUNK);
    u64*      msk1 = msk0 + (B / 64);

    // step 0: no pull
    fused_kernel<<<NBLK, NTHR, 0, stream>>>(inp, W1, b1, W2, b2, W3, b3,
                                            st0, cnt0, msk0,
                                            st0, cnt0, msk0, nullptr, 0);
    // steps 1..nsteps-1: pull prev (writes traj row t-1) + compute step t
    for (int t = 1; t < nsteps; ++t) {
        const bool odd = (t & 1);
        const float2*   stP  = odd ? st0  : st1;
        const unsigned* cntP = odd ? cnt0 : cnt1;
        const u64*      mskP = odd ? msk0 : msk1;
        float2*   stN  = odd ? st1  : st0;
        unsigned* cntN = odd ? cnt1 : cnt0;
        u64*      mskN = odd ? msk1 : msk0;
        fused_kernel<<<NBLK, NTHR, 0, stream>>>(inp, W1, b1, W2, b2, W3, b3,
                                                stP, cntP, mskP,
                                                stN, cntN, mskN,
                                                out + (size_t)(t - 1) * B, 1);
    }
    // final pull-only: traj row nsteps-1
    {
        const bool odd = (nsteps & 1);
        const float2*   stP  = odd ? st0  : st1;
        const unsigned* cntP = odd ? cnt0 : cnt1;
        const u64*      mskP = odd ? msk0 : msk1;
        fused_kernel<<<NBLK, NTHR, 0, stream>>>(inp, W1, b1, W2, b2, W3, b3,
                                                stP, cntP, mskP,
                                                st0, cnt0, msk0,
                                                out + (size_t)(nsteps - 1) * B, 2);
    }
}